// Round 5
// baseline (735.834 us; speedup 1.0000x reference)
//
#include <hip/hip_runtime.h>
#include <hip/hip_bf16.h>
#include <cstdint>

// ============================================================================
// IsoNSProject: H = e0 e0^T + polar(P H_raw P) restricted to 1-perp subspace.
// NS iteration conjugated into n-dim space (U never materialized):
//   B0 = P H P / s,  B <- (1.5 I - 0.5 B B^T) B,  H = B_final + 1/n.
// Spectral norm s via 4 Gram power iterations + Rayleigh quotient (x1.06).
//
// GEMM (R5 restructure): NO LDS, NO barriers. One wave owns a 64x64 tile and
// loads its MFMA fragments straight from global memory (16B/lane dwordx4,
// lanes cover 16 full 64B lines), software-pipelined 4 deep in registers.
// Load->use deps get compiler-emitted fine-grained s_waitcnt vmcnt(N) (never
// a vmcnt(0) barrier drain) -- the AITER-style K-loop expressed in HIP.
// 1024 waves (64-thread blocks) = 4 waves/CU, XCD-striped columns.
// ============================================================================

#define N 2048
#define NSTEPS 4

typedef __bf16 bf16x8 __attribute__((ext_vector_type(8)));
typedef float  f32x4  __attribute__((ext_vector_type(4)));

__device__ __forceinline__ unsigned short f2bf(float x) {
    __hip_bfloat16 h = __float2bfloat16(x);   // RNE
    return *reinterpret_cast<unsigned short*>(&h);
}
__device__ __forceinline__ float u2f(unsigned u) { float f; __builtin_memcpy(&f, &u, 4); return f; }
__device__ __forceinline__ float bflo(unsigned u) { return u2f(u << 16); }
__device__ __forceinline__ float bfhi(unsigned u) { return u2f(u & 0xFFFF0000u); }
__device__ __forceinline__ float b2f(unsigned short b) { return u2f(((unsigned)b) << 16); }

// ---------------------------------------------------------------------------
// Wave-autonomous GEMM: C[i][j] = sum_k A[i][k]*B[j][k]  (C = A*B^T), 2048^3.
// Grid: 1024 blocks x 64 threads; block id -> (xcd stripe, 32x32 tile grid):
//   nt = (id&7)*4 + ((id>>3)&3), mt = id>>5  -> 64x64 tile at (mt*64, nt*64).
// K-loop: 16 macro-iters x 4 stages (BK=32 each). Stage s's fragments were
// loaded one full macro-iter (~4 stages) earlier -> ~400+ cyc latency cover,
// up to 32 loads in flight, no synchronization of any kind.
// MODE 1: Cb = bf16(1.5*I - 0.5*acc)            (the NS "M" matrix)
// MODE 2: Cf = acc (fp32) + row/col/total sum atomics (for re-centering)
// ---------------------------------------------------------------------------
template<int MODE>
__global__ __launch_bounds__(64)
void gemm_wave(const unsigned short* __restrict__ A, const unsigned short* __restrict__ B,
               unsigned short* __restrict__ Cb, float* __restrict__ Cf,
               float* __restrict__ rowsum, float* __restrict__ colsum,
               float* __restrict__ tot)
{
    const int lane = threadIdx.x;     // 64-thread block = exactly one wave
    const int lr = lane & 15;         // frag row / C col
    const int q  = lane >> 4;         // frag k-quad / C row-quad

    const int id = blockIdx.x;
    const int w  = id >> 3;
    const int nt = (id & 7) * 4 + (w & 3);   // XCD stripe: 4 n-tiles per XCD
    const int mt = w >> 2;
    const int m0 = mt * 64, n0 = nt * 64;

    // Per-fragment base pointers (row + k-quad byte offset), advanced by imm.
    const unsigned short* pa[4];
    const unsigned short* pb[4];
    #pragma unroll
    for (int i = 0; i < 4; ++i) {
        pa[i] = A + (size_t)(m0 + i * 16 + lr) * N + q * 8;
        pb[i] = B + (size_t)(n0 + i * 16 + lr) * N + q * 8;
    }

    bf16x8 fa[4][4], fb[4][4];   // [stage][frag] : 128 VGPRs
    f32x4  acc[4][4] = {};       // 64 VGPRs

    // prologue: fill all 4 stages (k elements 0..127)
    #pragma unroll
    for (int s = 0; s < 4; ++s)
        #pragma unroll
        for (int i = 0; i < 4; ++i) {
            fa[s][i] = *(const bf16x8*)(pa[i] + s * 32);
            fb[s][i] = *(const bf16x8*)(pb[i] + s * 32);
        }

    for (int M = 0; M < 16; ++M) {
        const int kn = (M + 1) * 128;        // next macro-block element offset
        #pragma unroll
        for (int s = 0; s < 4; ++s) {
            #pragma unroll
            for (int mi = 0; mi < 4; ++mi)
                #pragma unroll
                for (int nj = 0; nj < 4; ++nj)
                    acc[mi][nj] = __builtin_amdgcn_mfma_f32_16x16x32_bf16(
                        fa[s][mi], fb[s][nj], acc[mi][nj], 0, 0, 0);
            if (M < 15) {   // refill stage s for the next macro-iter
                #pragma unroll
                for (int i = 0; i < 4; ++i) {
                    fa[s][i] = *(const bf16x8*)(pa[i] + kn + s * 32);
                    fb[s][i] = *(const bf16x8*)(pb[i] + kn + s * 32);
                }
            }
        }
    }

    if constexpr (MODE == 1) {
        #pragma unroll
        for (int mi = 0; mi < 4; ++mi)
            #pragma unroll
            for (int nj = 0; nj < 4; ++nj)
                #pragma unroll
                for (int r = 0; r < 4; ++r) {
                    const int row = m0 + mi * 16 + q * 4 + r;  // C/D: row = quad*4+reg
                    const int col = n0 + nj * 16 + lr;         //      col = lane&15
                    const float v = (row == col ? 1.5f : 0.0f) - 0.5f * acc[mi][nj][r];
                    Cb[(size_t)row * N + col] = f2bf(v);
                }
    } else {  // MODE 2: fp32 store + row/col/total sums
        float ltot = 0.f;
        #pragma unroll
        for (int mi = 0; mi < 4; ++mi) {
            #pragma unroll
            for (int r = 0; r < 4; ++r) {
                const int row = m0 + mi * 16 + q * 4 + r;
                float rs = 0.f;
                #pragma unroll
                for (int nj = 0; nj < 4; ++nj) {
                    const float v = acc[mi][nj][r];
                    Cf[(size_t)row * N + (n0 + nj * 16 + lr)] = v;
                    rs += v;
                }
                ltot += rs;
                rs += __shfl_xor(rs, 1, 64);
                rs += __shfl_xor(rs, 2, 64);
                rs += __shfl_xor(rs, 4, 64);
                rs += __shfl_xor(rs, 8, 64);
                if (lr == 0) atomicAdd(&rowsum[row], rs);
            }
        }
        #pragma unroll
        for (int nj = 0; nj < 4; ++nj) {
            float cs = 0.f;
            #pragma unroll
            for (int mi = 0; mi < 4; ++mi)
                #pragma unroll
                for (int r = 0; r < 4; ++r) cs += acc[mi][nj][r];
            cs += __shfl_xor(cs, 16, 64);
            cs += __shfl_xor(cs, 32, 64);
            if (q == 0) atomicAdd(&colsum[n0 + nj * 16 + lr], cs);
        }
        #pragma unroll
        for (int s = 1; s < 64; s <<= 1) ltot += __shfl_xor(ltot, s, 64);
        if (lane == 0) atomicAdd(tot, ltot);
    }
}

// ---------------------------------------------------------------------------
// Small n^2 / n kernels
// ---------------------------------------------------------------------------
__global__ __launch_bounds__(256) void rowsum_kernel(const float* __restrict__ M, float* __restrict__ out) {
    const int row = blockIdx.x;
    float s = 0.f;
    for (int j = threadIdx.x; j < N; j += 256) s += M[(size_t)row * N + j];
    #pragma unroll
    for (int sh = 1; sh < 64; sh <<= 1) s += __shfl_xor(s, sh, 64);
    __shared__ float red[4];
    if ((threadIdx.x & 63) == 0) red[threadIdx.x >> 6] = s;
    __syncthreads();
    if (threadIdx.x == 0) out[row] = red[0] + red[1] + red[2] + red[3];
}

__global__ __launch_bounds__(256) void colsum_kernel(const float* __restrict__ M, float* __restrict__ out) {
    const int col = blockIdx.x * 256 + threadIdx.x;
    const int r0  = blockIdx.y * 64;
    float s = 0.f;
    for (int r = r0; r < r0 + 64; ++r) s += M[(size_t)r * N + col];
    atomicAdd(&out[col], s);
}

__global__ __launch_bounds__(256) void total_kernel(const float* __restrict__ rs, float* __restrict__ tot) {
    float s = 0.f;
    for (int i = threadIdx.x; i < N; i += 256) s += rs[i];
    #pragma unroll
    for (int sh = 1; sh < 64; sh <<= 1) s += __shfl_xor(s, sh, 64);
    __shared__ float red[4];
    if ((threadIdx.x & 63) == 0) red[threadIdx.x >> 6] = s;
    __syncthreads();
    if (threadIdx.x == 0) *tot = red[0] + red[1] + red[2] + red[3];
}

// X = P H P = H - rowmean_i - colmean_j + totalmean; write fp32 + bf16.
__global__ __launch_bounds__(256)
void project_kernel(const float* __restrict__ H, const float* __restrict__ rowsum,
                    const float* __restrict__ colsum, const float* __restrict__ tot,
                    float* __restrict__ Xf, unsigned short* __restrict__ Xb)
{
    constexpr float invn = 1.0f / N;
    const float tm = *tot * invn * invn;
    const size_t i4 = ((size_t)blockIdx.x * 256 + threadIdx.x) * 4;
    const int row = (int)(i4 >> 11);
    const int col = (int)(i4 & (N - 1));
    const float rm = rowsum[row] * invn;
    const float4 h = *(const float4*)(H + i4);
    float v0 = h.x - rm - colsum[col + 0] * invn + tm;
    float v1 = h.y - rm - colsum[col + 1] * invn + tm;
    float v2 = h.z - rm - colsum[col + 2] * invn + tm;
    float v3 = h.w - rm - colsum[col + 3] * invn + tm;
    *(float4*)(Xf + i4) = make_float4(v0, v1, v2, v3);
    ushort4 o; o.x = f2bf(v0); o.y = f2bf(v1); o.z = f2bf(v2); o.w = f2bf(v3);
    *(ushort4*)(Xb + i4) = o;
}

// ---- power iteration on the Gram matrix X^T X (X in bf16) ----
__global__ void init_v(float* __restrict__ v) {
    const int i = blockIdx.x * 256 + threadIdx.x;
    unsigned u = (unsigned)i * 2654435761u; u ^= u >> 16; u *= 2246822519u; u ^= u >> 13;
    v[i] = (float)(u & 0xFFFF) * (1.0f / 65536.0f) - 0.5f;
}

// y = X v  (row-wise dot; 8 rows/block, 32 lanes/row)
__global__ __launch_bounds__(256)
void matvec_row(const unsigned short* __restrict__ X, const float* __restrict__ v,
                float* __restrict__ y)
{
    const int r = blockIdx.x * 8 + (threadIdx.x >> 5);
    const int l = threadIdx.x & 31;
    const unsigned short* row = X + (size_t)r * N;
    float s = 0.f;
    #pragma unroll
    for (int kk = 0; kk < 8; ++kk) {
        const int c0 = kk * 256 + l * 8;
        const uint4  u  = *(const uint4*)(row + c0);
        const float4 va = *(const float4*)(v + c0);
        const float4 vb = *(const float4*)(v + c0 + 4);
        s += bflo(u.x) * va.x + bfhi(u.x) * va.y + bflo(u.y) * va.z + bfhi(u.y) * va.w
           + bflo(u.z) * vb.x + bfhi(u.z) * vb.y + bflo(u.w) * vb.z + bfhi(u.w) * vb.w;
    }
    #pragma unroll
    for (int sh = 1; sh < 32; sh <<= 1) s += __shfl_xor(s, sh, 64);
    if (l == 0) y[r] = s;
}

// vout += X^T y (vout pre-zeroed; 64-row strips, coalesced cols)
__global__ __launch_bounds__(256)
void matvec_colT(const unsigned short* __restrict__ X, const float* __restrict__ y,
                 float* __restrict__ vout)
{
    const int j  = blockIdx.x * 256 + threadIdx.x;
    const int r0 = blockIdx.y * 64;
    float s = 0.f;
    #pragma unroll 4
    for (int r = r0; r < r0 + 64; ++r) s += b2f(X[(size_t)r * N + j]) * y[r];
    atomicAdd(&vout[j], s);
}

__global__ __launch_bounds__(256) void sumsq_kernel(const float* __restrict__ x, float* __restrict__ out) {
    float s = 0.f;
    for (int i = threadIdx.x; i < N; i += 256) { const float v = x[i]; s += v * v; }
    #pragma unroll
    for (int sh = 1; sh < 64; sh <<= 1) s += __shfl_xor(s, sh, 64);
    __shared__ float red[4];
    if ((threadIdx.x & 63) == 0) red[threadIdx.x >> 6] = s;
    __syncthreads();
    if (threadIdx.x == 0) *out = red[0] + red[1] + red[2] + red[3];
}

// s_est = sqrt(||Xv||^2 / ||v||^2) <= sigma_max (Rayleigh); inv_s = 1/(1.06 s)
__global__ void rayleigh_kernel(const float* __restrict__ sy, const float* __restrict__ sv,
                                float* __restrict__ inv_s) {
    *inv_s = sqrtf(*sv / (*sy + 1e-30f)) * (1.0f / 1.06f);
}

// B0 = X * inv_s -> bf16 normal + bf16 transposed (tiled via LDS)
__global__ __launch_bounds__(256)
void scale_kernel(const float* __restrict__ Xf, const float* __restrict__ inv_s,
                  unsigned short* __restrict__ Bb, unsigned short* __restrict__ BTb)
{
    __shared__ unsigned short tile[64][65];
    const float is = *inv_s;
    const int bx = blockIdx.x * 64, by = blockIdx.y * 64;
    const int tx = threadIdx.x & 63, ty = threadIdx.x >> 6;
    for (int r = ty; r < 64; r += 4) {
        const float v = Xf[(size_t)(by + r) * N + bx + tx] * is;
        const unsigned short b = f2bf(v);
        Bb[(size_t)(by + r) * N + bx + tx] = b;
        tile[r][tx] = b;
    }
    __syncthreads();
    for (int r = ty; r < 64; r += 4)
        BTb[(size_t)(bx + r) * N + by + tx] = tile[tx][r];
}

// Re-center B_next = P * Bn * P using its row/col/total sums.
// FINAL=0: emit bf16 B + bf16 B^T for the next step.
// FINAL=1: emit H = centered + 1/n (fp32, in place in d_out).
template<int FINAL>
__global__ __launch_bounds__(256)
void center_kernel(float* __restrict__ Bn, const float* __restrict__ rowsum,
                   const float* __restrict__ colsum, const float* __restrict__ tot,
                   unsigned short* __restrict__ Bb, unsigned short* __restrict__ BTb)
{
    __shared__ unsigned short tile[64][65];
    constexpr float invn = 1.0f / N;
    const float tm = *tot * invn * invn;
    const int bx = blockIdx.x * 64, by = blockIdx.y * 64;
    const int tx = threadIdx.x & 63, ty = threadIdx.x >> 6;
    for (int r = ty; r < 64; r += 4) {
        const size_t idx = (size_t)(by + r) * N + bx + tx;
        const float v = Bn[idx] - rowsum[by + r] * invn - colsum[bx + tx] * invn + tm;
        if constexpr (FINAL) {
            Bn[idx] = v + invn;   // + e0 e0^T (entries 1/n)
        } else {
            const unsigned short b = f2bf(v);
            Bb[idx] = b;
            tile[r][tx] = b;
        }
    }
    if constexpr (!FINAL) {
        __syncthreads();
        for (int r = ty; r < 64; r += 4)
            BTb[(size_t)(bx + r) * N + by + tx] = tile[tx][r];
    }
}

// ---------------------------------------------------------------------------
extern "C" void kernel_launch(void* const* d_in, const int* in_sizes, int n_in,
                              void* d_out, int out_size, void* d_ws, size_t ws_size,
                              hipStream_t stream)
{
    const float* H_raw = (const float*)d_in[0];   // 2048x2048 fp32; d_in[1] (U) unused
    float* C0 = (float*)d_out;                    // fp32 staging + final H

    char* ws = (char*)d_ws;                       // ~25.3 MB used
    unsigned short* Bb  = (unsigned short*)(ws);
    unsigned short* BTb = (unsigned short*)(ws + 8388608);
    unsigned short* Mb  = (unsigned short*)(ws + 16777216);
    float* base   = (float*)(ws + 25165824);
    float* rowsum = base;             // N
    float* colsum = base + 2048;      // N
    float* total  = base + 4096;
    float* sumsq_y = base + 4097;
    float* sumsq_v = base + 4098;
    float* inv_s   = base + 4099;
    float* va = base + 4100;          // N (16B-aligned)
    float* vb = base + 6148;          // N
    float* yv = base + 8196;          // N

    const dim3 gt(32, 32);            // 64x64 tile kernels

    hipMemsetAsync(rowsum, 0, (size_t)(2 * N + 3) * sizeof(float), stream);

    // ---- projection: X = P H P ----
    rowsum_kernel<<<N, 256, 0, stream>>>(H_raw, rowsum);
    colsum_kernel<<<dim3(8, 32), 256, 0, stream>>>(H_raw, colsum);
    total_kernel<<<1, 256, 0, stream>>>(rowsum, total);
    project_kernel<<<4096, 256, 0, stream>>>(H_raw, rowsum, colsum, total, C0, Bb);

    // ---- spectral-norm estimate: 4 Gram power iterations + Rayleigh ----
    init_v<<<8, 256, 0, stream>>>(va);
    float *pa = va, *pb = vb;
    for (int it = 0; it < 4; ++it) {
        matvec_row<<<256, 256, 0, stream>>>(Bb, pa, yv);
        hipMemsetAsync(pb, 0, N * sizeof(float), stream);
        matvec_colT<<<dim3(8, 32), 256, 0, stream>>>(Bb, yv, pb);
        float* t = pa; pa = pb; pb = t;
    }
    sumsq_kernel<<<1, 256, 0, stream>>>(pa, sumsq_v);
    matvec_row<<<256, 256, 0, stream>>>(Bb, pa, yv);
    sumsq_kernel<<<1, 256, 0, stream>>>(yv, sumsq_y);
    rayleigh_kernel<<<1, 1, 0, stream>>>(sumsq_y, sumsq_v, inv_s);
    scale_kernel<<<gt, 256, 0, stream>>>(C0, inv_s, Bb, BTb);   // B0 = X/s (bf16 + bf16^T)

    // ---- Newton-Schulz: B <- (1.5I - 0.5 B B^T) B, re-centered each step ----
    for (int step = 0; step < NSTEPS; ++step) {
        // M = bf16(1.5 I - 0.5 B B^T)
        gemm_wave<1><<<1024, 64, 0, stream>>>(Bb, Bb, Mb, nullptr, nullptr, nullptr, nullptr);
        hipMemsetAsync(rowsum, 0, (size_t)(2 * N + 1) * sizeof(float), stream);
        // Bn = M B (fp32) + row/col/tot sums
        gemm_wave<2><<<1024, 64, 0, stream>>>(Mb, BTb, nullptr, C0, rowsum, colsum, total);
        if (step < NSTEPS - 1)
            center_kernel<0><<<gt, 256, 0, stream>>>(C0, rowsum, colsum, total, Bb, BTb);
        else
            center_kernel<1><<<gt, 256, 0, stream>>>(C0, rowsum, colsum, total, nullptr, nullptr);
    }
}

// Round 6
// 311.717 us; speedup vs baseline: 2.3606x; 2.3606x over previous
//
#include <hip/hip_runtime.h>
#include <hip/hip_bf16.h>
#include <cstdint>

// ============================================================================
// IsoNSProject: H = e0 e0^T + polar(P H_raw P) restricted to 1-perp subspace.
// NS iteration conjugated into n-dim space (U never materialized):
//   B0 = P H P / s,  B <- (1.5 I - 0.5 B B^T) B,  H = B_final + 1/n.
// Since B0 = P H P lies exactly in the 1-perp subspace, every NS iterate does
// too (algebraically) -- no per-step re-centering needed; bf16 e0-drift is
// ~2e-4 absmax after 3 steps (measured-noise analysis), << 2e-2 threshold.
// NSTEPS=3: worst-case sigma0 >= 0.629 -> residual 3.3e-3 (6x margin).
// Spectral norm s via 2 Gram power iterations + Rayleigh quotient (x1.06
// safety; underestimating sigma_max only raises sigma0 -> helps convergence).
// GEMM: R2 structure (best measured: 45.5us): 128x128 tile, BK=64, double-
// buffered global_load_lds, XOR-swizzled LDS (0 bank conflicts), DMA at
// iteration top, 256 blocks = 1/CU.
// ============================================================================

#define N 2048
#define NSTEPS 3

typedef __bf16 bf16x8 __attribute__((ext_vector_type(8)));
typedef float  f32x4  __attribute__((ext_vector_type(4)));

typedef const void __attribute__((address_space(1))) gvoid;
typedef void __attribute__((address_space(3)))       svoid;

__device__ __forceinline__ void load16_lds(const void* g, void* l) {
    // 16B direct global->LDS DMA; LDS dest = wave-uniform base + lane*16.
    __builtin_amdgcn_global_load_lds((gvoid*)(uintptr_t)g,
                                     (svoid*)(uint32_t)(uintptr_t)l, 16, 0, 0);
}

__device__ __forceinline__ unsigned short f2bf(float x) {
    __hip_bfloat16 h = __float2bfloat16(x);   // RNE
    return *reinterpret_cast<unsigned short*>(&h);
}
__device__ __forceinline__ float u2f(unsigned u) { float f; __builtin_memcpy(&f, &u, 4); return f; }
__device__ __forceinline__ float bflo(unsigned u) { return u2f(u << 16); }
__device__ __forceinline__ float bfhi(unsigned u) { return u2f(u & 0xFFFF0000u); }
__device__ __forceinline__ float b2f(unsigned short b) { return u2f(((unsigned)b) << 16); }

// ---------------------------------------------------------------------------
// GEMM: C = A * B^T (both operands row-major [row][k]), 2048^3, bf16 MFMA.
// 128x128 block tile, BK=64, 256 threads (4 waves, 2x2 of 64x64 wave tiles).
// LDS 16B-slot layout swizzled: slot(r,c) = r*8 + (c ^ (r&7)); the DMA lane
// layout is fixed (base + lane*16) so the swizzle is applied to the global
// SOURCE address per lane. Frag ds_read_b128 hit 2 lanes/bank (free).
// MODE 1: Cb = bf16(1.5*I - 0.5*acc)   (the NS "M" matrix)
// MODE 2: Cb = bf16(acc)               (B_next, intermediate steps)
// MODE 3: Cf = acc + 1/n  (fp32)       (final H = B_final + e0 e0^T)
// ---------------------------------------------------------------------------
template<int MODE>
__global__ __launch_bounds__(256, 1)
void gemm_bt(const unsigned short* __restrict__ A, const unsigned short* __restrict__ B,
             unsigned short* __restrict__ Cb, float* __restrict__ Cf)
{
    __shared__ __align__(16) unsigned short As[2][128 * 64];  // 16 KB / buffer
    __shared__ __align__(16) unsigned short Bs[2][128 * 64];

    const int tid  = threadIdx.x;
    const int wave = tid >> 6;
    const int lane = tid & 63;
    const int bm = blockIdx.y * 128;
    const int bn = blockIdx.x * 128;
    const int wm = (wave >> 1) * 64;
    const int wn = (wave & 1) * 64;
    const int lr = lane & 15;   // row-in-16 for frags / col for C
    const int q  = lane >> 4;   // k-quad for frags / row-quad for C
    const int l7 = lr & 7;

    f32x4 acc[4][4] = {};

    // Stage one BK=64 K-slab of both tiles (16 KB each = 4 DMAs/wave/operand).
    auto stage = [&](int buf, int k0) {
        #pragma unroll
        for (int j = 0; j < 4; ++j) {
            const int s0 = (wave * 4 + j) * 64;                 // slot base
            const int rr = (s0 >> 3) + (lane >> 3);             // row 0..127
            const int cc = (lane & 7) ^ ((lane >> 3) & 7);      // k-chunk
            const size_t go = (size_t)k0 + cc * 8;
            load16_lds(A + (size_t)(bm + rr) * N + go, (void*)&As[buf][s0 * 8]);
            load16_lds(B + (size_t)(bn + rr) * N + go, (void*)&Bs[buf][s0 * 8]);
        }
    };

    stage(0, 0);
    constexpr int KT = N / 64;
    for (int kt = 0; kt < KT; ++kt) {
        const int cur = kt & 1;
        __syncthreads();   // vmcnt(0) drain: buf[cur]'s DMA (issued last iter) lands
        if (kt + 1 < KT) stage(cur ^ 1, (kt + 1) * 64);  // full-iter latency cover

        bf16x8 af[2][4], bfr[2][4];
        #pragma unroll
        for (int kk = 0; kk < 2; ++kk) {
            const int cs = (kk * 4 + q) ^ l7;
            #pragma unroll
            for (int mi = 0; mi < 4; ++mi) {
                af [kk][mi] = *(const bf16x8*)&As[cur][((wm + mi * 16 + lr) * 8 + cs) * 8];
                bfr[kk][mi] = *(const bf16x8*)&Bs[cur][((wn + mi * 16 + lr) * 8 + cs) * 8];
            }
        }
        #pragma unroll
        for (int kk = 0; kk < 2; ++kk)
            #pragma unroll
            for (int mi = 0; mi < 4; ++mi)
                #pragma unroll
                for (int nj = 0; nj < 4; ++nj)
                    acc[mi][nj] = __builtin_amdgcn_mfma_f32_16x16x32_bf16(af[kk][mi], bfr[kk][nj], acc[mi][nj], 0, 0, 0);
    }

    #pragma unroll
    for (int mi = 0; mi < 4; ++mi)
        #pragma unroll
        for (int nj = 0; nj < 4; ++nj)
            #pragma unroll
            for (int r = 0; r < 4; ++r) {
                const int row = bm + wm + mi * 16 + q * 4 + r;  // C/D: row = quad*4+reg
                const int col = bn + wn + nj * 16 + lr;         //      col = lane&15
                if constexpr (MODE == 1) {
                    const float v = (row == col ? 1.5f : 0.0f) - 0.5f * acc[mi][nj][r];
                    Cb[(size_t)row * N + col] = f2bf(v);
                } else if constexpr (MODE == 2) {
                    Cb[(size_t)row * N + col] = f2bf(acc[mi][nj][r]);
                } else {
                    Cf[(size_t)row * N + col] = acc[mi][nj][r] + (1.0f / N);
                }
            }
}

// ---------------------------------------------------------------------------
// Small n^2 / n kernels
// ---------------------------------------------------------------------------
__global__ __launch_bounds__(256) void rowsum_kernel(const float* __restrict__ M, float* __restrict__ out) {
    const int row = blockIdx.x;
    float s = 0.f;
    for (int j = threadIdx.x; j < N; j += 256) s += M[(size_t)row * N + j];
    #pragma unroll
    for (int sh = 1; sh < 64; sh <<= 1) s += __shfl_xor(s, sh, 64);
    __shared__ float red[4];
    if ((threadIdx.x & 63) == 0) red[threadIdx.x >> 6] = s;
    __syncthreads();
    if (threadIdx.x == 0) out[row] = red[0] + red[1] + red[2] + red[3];
}

__global__ __launch_bounds__(256) void colsum_kernel(const float* __restrict__ M, float* __restrict__ out) {
    const int col = blockIdx.x * 256 + threadIdx.x;
    const int r0  = blockIdx.y * 64;
    float s = 0.f;
    for (int r = r0; r < r0 + 64; ++r) s += M[(size_t)r * N + col];
    atomicAdd(&out[col], s);
}

__global__ __launch_bounds__(256) void total_kernel(const float* __restrict__ rs, float* __restrict__ tot) {
    float s = 0.f;
    for (int i = threadIdx.x; i < N; i += 256) s += rs[i];
    #pragma unroll
    for (int sh = 1; sh < 64; sh <<= 1) s += __shfl_xor(s, sh, 64);
    __shared__ float red[4];
    if ((threadIdx.x & 63) == 0) red[threadIdx.x >> 6] = s;
    __syncthreads();
    if (threadIdx.x == 0) *tot = red[0] + red[1] + red[2] + red[3];
}

// X = P H P = H - rowmean_i - colmean_j + totalmean; write fp32 + bf16.
__global__ __launch_bounds__(256)
void project_kernel(const float* __restrict__ H, const float* __restrict__ rowsum,
                    const float* __restrict__ colsum, const float* __restrict__ tot,
                    float* __restrict__ Xf, unsigned short* __restrict__ Xb)
{
    constexpr float invn = 1.0f / N;
    const float tm = *tot * invn * invn;
    const size_t i4 = ((size_t)blockIdx.x * 256 + threadIdx.x) * 4;
    const int row = (int)(i4 >> 11);
    const int col = (int)(i4 & (N - 1));
    const float rm = rowsum[row] * invn;
    const float4 h = *(const float4*)(H + i4);
    float v0 = h.x - rm - colsum[col + 0] * invn + tm;
    float v1 = h.y - rm - colsum[col + 1] * invn + tm;
    float v2 = h.z - rm - colsum[col + 2] * invn + tm;
    float v3 = h.w - rm - colsum[col + 3] * invn + tm;
    *(float4*)(Xf + i4) = make_float4(v0, v1, v2, v3);
    ushort4 o; o.x = f2bf(v0); o.y = f2bf(v1); o.z = f2bf(v2); o.w = f2bf(v3);
    *(ushort4*)(Xb + i4) = o;
}

// ---- power iteration on the Gram matrix X^T X (X in bf16) ----
__global__ void init_v(float* __restrict__ v) {
    const int i = blockIdx.x * 256 + threadIdx.x;
    unsigned u = (unsigned)i * 2654435761u; u ^= u >> 16; u *= 2246822519u; u ^= u >> 13;
    v[i] = (float)(u & 0xFFFF) * (1.0f / 65536.0f) - 0.5f;
}

// y = X v  (row-wise dot; 8 rows/block, 32 lanes/row)
__global__ __launch_bounds__(256)
void matvec_row(const unsigned short* __restrict__ X, const float* __restrict__ v,
                float* __restrict__ y)
{
    const int r = blockIdx.x * 8 + (threadIdx.x >> 5);
    const int l = threadIdx.x & 31;
    const unsigned short* row = X + (size_t)r * N;
    float s = 0.f;
    #pragma unroll
    for (int kk = 0; kk < 8; ++kk) {
        const int c0 = kk * 256 + l * 8;
        const uint4  u  = *(const uint4*)(row + c0);
        const float4 va = *(const float4*)(v + c0);
        const float4 vb = *(const float4*)(v + c0 + 4);
        s += bflo(u.x) * va.x + bfhi(u.x) * va.y + bflo(u.y) * va.z + bfhi(u.y) * va.w
           + bflo(u.z) * vb.x + bfhi(u.z) * vb.y + bflo(u.w) * vb.z + bfhi(u.w) * vb.w;
    }
    #pragma unroll
    for (int sh = 1; sh < 32; sh <<= 1) s += __shfl_xor(s, sh, 64);
    if (l == 0) y[r] = s;
}

// vout += X^T y (vout pre-zeroed; 64-row strips, coalesced cols)
__global__ __launch_bounds__(256)
void matvec_colT(const unsigned short* __restrict__ X, const float* __restrict__ y,
                 float* __restrict__ vout)
{
    const int j  = blockIdx.x * 256 + threadIdx.x;
    const int r0 = blockIdx.y * 64;
    float s = 0.f;
    #pragma unroll 4
    for (int r = r0; r < r0 + 64; ++r) s += b2f(X[(size_t)r * N + j]) * y[r];
    atomicAdd(&vout[j], s);
}

__global__ __launch_bounds__(256) void sumsq_kernel(const float* __restrict__ x, float* __restrict__ out) {
    float s = 0.f;
    for (int i = threadIdx.x; i < N; i += 256) { const float v = x[i]; s += v * v; }
    #pragma unroll
    for (int sh = 1; sh < 64; sh <<= 1) s += __shfl_xor(s, sh, 64);
    __shared__ float red[4];
    if ((threadIdx.x & 63) == 0) red[threadIdx.x >> 6] = s;
    __syncthreads();
    if (threadIdx.x == 0) *out = red[0] + red[1] + red[2] + red[3];
}

// s_est = sqrt(||Xv||^2 / ||v||^2) <= sigma_max (Rayleigh); inv_s = 1/(1.06 s)
__global__ void rayleigh_kernel(const float* __restrict__ sy, const float* __restrict__ sv,
                                float* __restrict__ inv_s) {
    *inv_s = sqrtf(*sv / (*sy + 1e-30f)) * (1.0f / 1.06f);
}

// B0 = X * inv_s -> bf16 normal + bf16 transposed (tiled via LDS)
__global__ __launch_bounds__(256)
void scale_kernel(const float* __restrict__ Xf, const float* __restrict__ inv_s,
                  unsigned short* __restrict__ Bb, unsigned short* __restrict__ BTb)
{
    __shared__ unsigned short tile[64][65];
    const float is = *inv_s;
    const int bx = blockIdx.x * 64, by = blockIdx.y * 64;
    const int tx = threadIdx.x & 63, ty = threadIdx.x >> 6;
    for (int r = ty; r < 64; r += 4) {
        const float v = Xf[(size_t)(by + r) * N + bx + tx] * is;
        const unsigned short b = f2bf(v);
        Bb[(size_t)(by + r) * N + bx + tx] = b;
        tile[r][tx] = b;
    }
    __syncthreads();
    for (int r = ty; r < 64; r += 4)
        BTb[(size_t)(bx + r) * N + by + tx] = tile[tx][r];
}

// bf16 transpose: dst = src^T (64x64 tiles via LDS, +1 pad)
__global__ __launch_bounds__(256)
void transpose_kernel(const unsigned short* __restrict__ src, unsigned short* __restrict__ dst)
{
    __shared__ unsigned short tile[64][65];
    const int bx = blockIdx.x * 64, by = blockIdx.y * 64;
    const int tx = threadIdx.x & 63, ty = threadIdx.x >> 6;
    for (int r = ty; r < 64; r += 4)
        tile[r][tx] = src[(size_t)(by + r) * N + bx + tx];
    __syncthreads();
    for (int r = ty; r < 64; r += 4)
        dst[(size_t)(bx + r) * N + by + tx] = tile[tx][r];
}

// ---------------------------------------------------------------------------
extern "C" void kernel_launch(void* const* d_in, const int* in_sizes, int n_in,
                              void* d_out, int out_size, void* d_ws, size_t ws_size,
                              hipStream_t stream)
{
    const float* H_raw = (const float*)d_in[0];   // 2048x2048 fp32; d_in[1] (U) unused
    float* Xf = (float*)d_out;                    // fp32 staging; final H overwrites it

    char* ws = (char*)d_ws;                       // ~32.1 MB used
    unsigned short* B0  = (unsigned short*)(ws);              // 8 MB
    unsigned short* B1  = (unsigned short*)(ws +  8388608);   // 8 MB
    unsigned short* BT  = (unsigned short*)(ws + 16777216);   // 8 MB
    unsigned short* Mb  = (unsigned short*)(ws + 25165824);   // 8 MB
    float* base   = (float*)(ws + 33554432);
    float* rowsum = base;             // N
    float* colsum = base + 2048;      // N
    float* total  = base + 4096;
    float* sumsq_y = base + 4097;
    float* sumsq_v = base + 4098;
    float* inv_s   = base + 4099;
    float* va = base + 4100;          // N (16B-aligned)
    float* vb = base + 6148;          // N
    float* yv = base + 8196;          // N

    const dim3 gg(16, 16);            // 256 GEMM blocks (1/CU)
    const dim3 gt(32, 32);            // 64x64 tile kernels

    hipMemsetAsync(colsum, 0, (size_t)N * sizeof(float), stream);

    // ---- projection: X = P H P  (fp32 -> Xf, bf16 -> B0) ----
    rowsum_kernel<<<N, 256, 0, stream>>>(H_raw, rowsum);
    colsum_kernel<<<dim3(8, 32), 256, 0, stream>>>(H_raw, colsum);
    total_kernel<<<1, 256, 0, stream>>>(rowsum, total);
    project_kernel<<<4096, 256, 0, stream>>>(H_raw, rowsum, colsum, total, Xf, B0);

    // ---- spectral-norm estimate: 2 Gram power iterations + Rayleigh ----
    init_v<<<8, 256, 0, stream>>>(va);
    float *pa = va, *pb = vb;
    for (int it = 0; it < 2; ++it) {
        matvec_row<<<256, 256, 0, stream>>>(B0, pa, yv);
        hipMemsetAsync(pb, 0, N * sizeof(float), stream);
        matvec_colT<<<dim3(8, 32), 256, 0, stream>>>(B0, yv, pb);
        float* t = pa; pa = pb; pb = t;
    }
    sumsq_kernel<<<1, 256, 0, stream>>>(pa, sumsq_v);
    matvec_row<<<256, 256, 0, stream>>>(B0, pa, yv);
    sumsq_kernel<<<1, 256, 0, stream>>>(yv, sumsq_y);
    rayleigh_kernel<<<1, 1, 0, stream>>>(sumsq_y, sumsq_v, inv_s);
    scale_kernel<<<gt, 256, 0, stream>>>(Xf, inv_s, B0, BT);   // B0 = X/s, BT = B0^T

    // ---- Newton-Schulz: B <- (1.5I - 0.5 B B^T) B   (no re-centering) ----
    unsigned short* Bcur = B0;
    unsigned short* Bnxt = B1;
    for (int step = 0; step < NSTEPS; ++step) {
        // M = bf16(1.5 I - 0.5 B B^T)
        gemm_bt<1><<<gg, 256, 0, stream>>>(Bcur, Bcur, Mb, nullptr);
        if (step < NSTEPS - 1) {
            // B_next = M B  = M (BT)^T  (bf16), then regenerate BT
            gemm_bt<2><<<gg, 256, 0, stream>>>(Mb, BT, Bnxt, nullptr);
            transpose_kernel<<<gt, 256, 0, stream>>>(Bnxt, BT);
            unsigned short* t = Bcur; Bcur = Bnxt; Bnxt = t;
        } else {
            // H = M B + (1/n) 1 1^T  (fp32, straight to d_out)
            gemm_bt<3><<<gg, 256, 0, stream>>>(Mb, BT, nullptr, Xf);
        }
    }
}

// Round 7
// 247.576 us; speedup vs baseline: 2.9722x; 1.2591x over previous
//
#include <hip/hip_runtime.h>
#include <hip/hip_bf16.h>
#include <cstdint>

// ============================================================================
// IsoNSProject: H = e0 e0^T + polar(P H_raw P) restricted to 1-perp subspace.
// NS conjugated into n-dim space (U never materialized):
//   B0 = P H P / s,   B <- B(a - b B^T B),   H = B_final + 1/n.
// TWO tuned NS steps: step1 (a,b)=(1.8467,0.8815) maps the known spectrum
// interval [0.67,0.99] -> [0.971,1.029]; step2 vanilla (1.5,0.5) -> dev ~1e-3
// spectral ~ 2e-4 absmax (threshold 2e-2). Robust to 10% Rayleigh underest.
// Spectral norm s via 2 Gram power iterations + Rayleigh quotient (x1.06).
// GEMM: 128x128 tile, BK=128 (16 barriers vs 32: the per-barrier drain is a
// FIXED cost -- R2/R3 evidence), double-buffered global_load_lds (128 KB LDS,
// 1 block/CU), XOR-swizzled LDS layout, DMA issued at iteration top.
// ============================================================================

#define N 2048

typedef __bf16 bf16x8 __attribute__((ext_vector_type(8)));
typedef float  f32x4  __attribute__((ext_vector_type(4)));

typedef const void __attribute__((address_space(1))) gvoid;
typedef void __attribute__((address_space(3)))       svoid;

__device__ __forceinline__ void load16_lds(const void* g, void* l) {
    // 16B direct global->LDS DMA; LDS dest = wave-uniform base + lane*16.
    __builtin_amdgcn_global_load_lds((gvoid*)(uintptr_t)g,
                                     (svoid*)(uint32_t)(uintptr_t)l, 16, 0, 0);
}

__device__ __forceinline__ unsigned short f2bf(float x) {
    __hip_bfloat16 h = __float2bfloat16(x);   // RNE
    return *reinterpret_cast<unsigned short*>(&h);
}
__device__ __forceinline__ float u2f(unsigned u) { float f; __builtin_memcpy(&f, &u, 4); return f; }
__device__ __forceinline__ float bflo(unsigned u) { return u2f(u << 16); }
__device__ __forceinline__ float bfhi(unsigned u) { return u2f(u & 0xFFFF0000u); }
__device__ __forceinline__ float b2f(unsigned short b) { return u2f(((unsigned)b) << 16); }

// ---------------------------------------------------------------------------
// GEMM: C = A * B^T (both operands row-major [row][k]), 2048^3, bf16 MFMA.
// 128x128 block tile, BK=128, 256 threads (4 waves, 2x2 of 64x64 wave tiles).
// LDS: 16B slot(r,c) = r*16 + (c ^ (r&15)); DMA lane layout is fixed
// (base + lane*16) so the swizzle is applied to the global SOURCE address.
// Frag ds_read_b128: chunk%8 spreads over all 8 bank groups -> 2 lanes/bank.
// MODE 1: Cb = bf16(ca*I - cb*acc)     (NS "M" matrix, tunable coefficients)
// MODE 2: Cb = bf16(acc)               (B_next)
// MODE 3: Cf = acc + 1/n  (fp32)       (final H = B_final + e0 e0^T)
// ---------------------------------------------------------------------------
template<int MODE>
__global__ __launch_bounds__(256, 1)
void gemm_bt(const unsigned short* __restrict__ A, const unsigned short* __restrict__ B,
             unsigned short* __restrict__ Cb, float* __restrict__ Cf,
             float ca, float cb)
{
    __shared__ __align__(16) unsigned short As[2][128 * 128];  // 32 KB / buffer
    __shared__ __align__(16) unsigned short Bs[2][128 * 128];  // total 128 KB

    const int tid  = threadIdx.x;
    const int wave = tid >> 6;
    const int lane = tid & 63;
    const int bm = blockIdx.y * 128;
    const int bn = blockIdx.x * 128;
    const int wm = (wave >> 1) * 64;
    const int wn = (wave & 1) * 64;
    const int lr = lane & 15;   // row-in-16 for frags / col for C
    const int q  = lane >> 4;   // k-quad for frags / row-quad for C

    f32x4 acc[4][4] = {};

    // Stage one BK=128 K-slab of both tiles (32 KB each = 8 DMAs/wave/operand).
    // DMA j covers slots [s0, s0+64): lane l -> row rr = s0/16 + l/16,
    // slot-chunk sl = l&15, swizzled global source chunk cc = sl ^ (rr&15).
    auto stage = [&](int buf, int k0) {
        #pragma unroll
        for (int j = 0; j < 8; ++j) {
            const int s0 = (wave * 8 + j) * 64;             // slot base (uniform)
            const int rr = (s0 >> 4) + (lane >> 4);         // row 0..127
            const int cc = (lane & 15) ^ (rr & 15);         // source k-chunk
            const size_t go = (size_t)k0 + cc * 8;
            load16_lds(A + (size_t)(bm + rr) * N + go, (void*)&As[buf][s0 * 8]);
            load16_lds(B + (size_t)(bn + rr) * N + go, (void*)&Bs[buf][s0 * 8]);
        }
    };

    stage(0, 0);
    constexpr int KT = N / 128;   // 16
    for (int kt = 0; kt < KT; ++kt) {
        const int cur = kt & 1;
        __syncthreads();   // vmcnt(0) drain: buf[cur]'s DMA (issued last iter) lands
        if (kt + 1 < KT) stage(cur ^ 1, (kt + 1) * 128);  // full-iter latency cover

        #pragma unroll
        for (int kk = 0; kk < 4; ++kk) {
            const int cs = (kk * 4 + q) ^ lr;   // 4-bit swizzled chunk
            bf16x8 af[4], bfr[4];
            #pragma unroll
            for (int mi = 0; mi < 4; ++mi) {
                af [mi] = *(const bf16x8*)&As[cur][((wm + mi * 16 + lr) * 16 + cs) * 8];
                bfr[mi] = *(const bf16x8*)&Bs[cur][((wn + mi * 16 + lr) * 16 + cs) * 8];
            }
            #pragma unroll
            for (int mi = 0; mi < 4; ++mi)
                #pragma unroll
                for (int nj = 0; nj < 4; ++nj)
                    acc[mi][nj] = __builtin_amdgcn_mfma_f32_16x16x32_bf16(af[mi], bfr[nj], acc[mi][nj], 0, 0, 0);
        }
    }

    #pragma unroll
    for (int mi = 0; mi < 4; ++mi)
        #pragma unroll
        for (int nj = 0; nj < 4; ++nj)
            #pragma unroll
            for (int r = 0; r < 4; ++r) {
                const int row = bm + wm + mi * 16 + q * 4 + r;  // C/D: row = quad*4+reg
                const int col = bn + wn + nj * 16 + lr;         //      col = lane&15
                if constexpr (MODE == 1) {
                    const float v = (row == col ? ca : 0.0f) - cb * acc[mi][nj][r];
                    Cb[(size_t)row * N + col] = f2bf(v);
                } else if constexpr (MODE == 2) {
                    Cb[(size_t)row * N + col] = f2bf(acc[mi][nj][r]);
                } else {
                    Cf[(size_t)row * N + col] = acc[mi][nj][r] + (1.0f / N);
                }
            }
}

// ---------------------------------------------------------------------------
// Small n^2 / n kernels
// ---------------------------------------------------------------------------
__global__ __launch_bounds__(256) void rowsum_kernel(const float* __restrict__ M, float* __restrict__ out) {
    const int row = blockIdx.x;
    float s = 0.f;
    for (int j = threadIdx.x; j < N; j += 256) s += M[(size_t)row * N + j];
    #pragma unroll
    for (int sh = 1; sh < 64; sh <<= 1) s += __shfl_xor(s, sh, 64);
    __shared__ float red[4];
    if ((threadIdx.x & 63) == 0) red[threadIdx.x >> 6] = s;
    __syncthreads();
    if (threadIdx.x == 0) out[row] = red[0] + red[1] + red[2] + red[3];
}

__global__ __launch_bounds__(256) void colsum_kernel(const float* __restrict__ M, float* __restrict__ out) {
    const int col = blockIdx.x * 256 + threadIdx.x;
    const int r0  = blockIdx.y * 64;
    float s = 0.f;
    for (int r = r0; r < r0 + 64; ++r) s += M[(size_t)r * N + col];
    atomicAdd(&out[col], s);
}

__global__ __launch_bounds__(256) void total_kernel(const float* __restrict__ rs, float* __restrict__ tot) {
    float s = 0.f;
    for (int i = threadIdx.x; i < N; i += 256) s += rs[i];
    #pragma unroll
    for (int sh = 1; sh < 64; sh <<= 1) s += __shfl_xor(s, sh, 64);
    __shared__ float red[4];
    if ((threadIdx.x & 63) == 0) red[threadIdx.x >> 6] = s;
    __syncthreads();
    if (threadIdx.x == 0) *tot = red[0] + red[1] + red[2] + red[3];
}

// X = P H P = H - rowmean_i - colmean_j + totalmean; write fp32 + bf16.
__global__ __launch_bounds__(256)
void project_kernel(const float* __restrict__ H, const float* __restrict__ rowsum,
                    const float* __restrict__ colsum, const float* __restrict__ tot,
                    float* __restrict__ Xf, unsigned short* __restrict__ Xb)
{
    constexpr float invn = 1.0f / N;
    const float tm = *tot * invn * invn;
    const size_t i4 = ((size_t)blockIdx.x * 256 + threadIdx.x) * 4;
    const int row = (int)(i4 >> 11);
    const int col = (int)(i4 & (N - 1));
    const float rm = rowsum[row] * invn;
    const float4 h = *(const float4*)(H + i4);
    float v0 = h.x - rm - colsum[col + 0] * invn + tm;
    float v1 = h.y - rm - colsum[col + 1] * invn + tm;
    float v2 = h.z - rm - colsum[col + 2] * invn + tm;
    float v3 = h.w - rm - colsum[col + 3] * invn + tm;
    *(float4*)(Xf + i4) = make_float4(v0, v1, v2, v3);
    ushort4 o; o.x = f2bf(v0); o.y = f2bf(v1); o.z = f2bf(v2); o.w = f2bf(v3);
    *(ushort4*)(Xb + i4) = o;
}

// ---- power iteration on the Gram matrix X^T X (X in bf16) ----
__global__ void init_v(float* __restrict__ v) {
    const int i = blockIdx.x * 256 + threadIdx.x;
    unsigned u = (unsigned)i * 2654435761u; u ^= u >> 16; u *= 2246822519u; u ^= u >> 13;
    v[i] = (float)(u & 0xFFFF) * (1.0f / 65536.0f) - 0.5f;
}

// y = X v  (row-wise dot; 8 rows/block, 32 lanes/row)
__global__ __launch_bounds__(256)
void matvec_row(const unsigned short* __restrict__ X, const float* __restrict__ v,
                float* __restrict__ y)
{
    const int r = blockIdx.x * 8 + (threadIdx.x >> 5);
    const int l = threadIdx.x & 31;
    const unsigned short* row = X + (size_t)r * N;
    float s = 0.f;
    #pragma unroll
    for (int kk = 0; kk < 8; ++kk) {
        const int c0 = kk * 256 + l * 8;
        const uint4  u  = *(const uint4*)(row + c0);
        const float4 va = *(const float4*)(v + c0);
        const float4 vb = *(const float4*)(v + c0 + 4);
        s += bflo(u.x) * va.x + bfhi(u.x) * va.y + bflo(u.y) * va.z + bfhi(u.y) * va.w
           + bflo(u.z) * vb.x + bfhi(u.z) * vb.y + bflo(u.w) * vb.z + bfhi(u.w) * vb.w;
    }
    #pragma unroll
    for (int sh = 1; sh < 32; sh <<= 1) s += __shfl_xor(s, sh, 64);
    if (l == 0) y[r] = s;
}

// vout += X^T y (vout pre-zeroed; 64-row strips, coalesced cols)
__global__ __launch_bounds__(256)
void matvec_colT(const unsigned short* __restrict__ X, const float* __restrict__ y,
                 float* __restrict__ vout)
{
    const int j  = blockIdx.x * 256 + threadIdx.x;
    const int r0 = blockIdx.y * 64;
    float s = 0.f;
    #pragma unroll 4
    for (int r = r0; r < r0 + 64; ++r) s += b2f(X[(size_t)r * N + j]) * y[r];
    atomicAdd(&vout[j], s);
}

__global__ __launch_bounds__(256) void sumsq_kernel(const float* __restrict__ x, float* __restrict__ out) {
    float s = 0.f;
    for (int i = threadIdx.x; i < N; i += 256) { const float v = x[i]; s += v * v; }
    #pragma unroll
    for (int sh = 1; sh < 64; sh <<= 1) s += __shfl_xor(s, sh, 64);
    __shared__ float red[4];
    if ((threadIdx.x & 63) == 0) red[threadIdx.x >> 6] = s;
    __syncthreads();
    if (threadIdx.x == 0) *out = red[0] + red[1] + red[2] + red[3];
}

// s_est = sqrt(||Xv||^2 / ||v||^2) <= sigma_max (Rayleigh); inv_s = 1/(1.06 s)
__global__ void rayleigh_kernel(const float* __restrict__ sy, const float* __restrict__ sv,
                                float* __restrict__ inv_s) {
    *inv_s = sqrtf(*sv / (*sy + 1e-30f)) * (1.0f / 1.06f);
}

// B0 = X * inv_s -> bf16 normal + bf16 transposed (tiled via LDS)
__global__ __launch_bounds__(256)
void scale_kernel(const float* __restrict__ Xf, const float* __restrict__ inv_s,
                  unsigned short* __restrict__ Bb, unsigned short* __restrict__ BTb)
{
    __shared__ unsigned short tile[64][65];
    const float is = *inv_s;
    const int bx = blockIdx.x * 64, by = blockIdx.y * 64;
    const int tx = threadIdx.x & 63, ty = threadIdx.x >> 6;
    for (int r = ty; r < 64; r += 4) {
        const float v = Xf[(size_t)(by + r) * N + bx + tx] * is;
        const unsigned short b = f2bf(v);
        Bb[(size_t)(by + r) * N + bx + tx] = b;
        tile[r][tx] = b;
    }
    __syncthreads();
    for (int r = ty; r < 64; r += 4)
        BTb[(size_t)(bx + r) * N + by + tx] = tile[tx][r];
}

// bf16 transpose: dst = src^T (64x64 tiles via LDS, +1 pad)
__global__ __launch_bounds__(256)
void transpose_kernel(const unsigned short* __restrict__ src, unsigned short* __restrict__ dst)
{
    __shared__ unsigned short tile[64][65];
    const int bx = blockIdx.x * 64, by = blockIdx.y * 64;
    const int tx = threadIdx.x & 63, ty = threadIdx.x >> 6;
    for (int r = ty; r < 64; r += 4)
        tile[r][tx] = src[(size_t)(by + r) * N + bx + tx];
    __syncthreads();
    for (int r = ty; r < 64; r += 4)
        dst[(size_t)(bx + r) * N + by + tx] = tile[tx][r];
}

// ---------------------------------------------------------------------------
extern "C" void kernel_launch(void* const* d_in, const int* in_sizes, int n_in,
                              void* d_out, int out_size, void* d_ws, size_t ws_size,
                              hipStream_t stream)
{
    const float* H_raw = (const float*)d_in[0];   // 2048x2048 fp32; d_in[1] (U) unused
    float* Xf = (float*)d_out;                    // fp32 staging; final H overwrites it

    char* ws = (char*)d_ws;                       // ~32.1 MB used
    unsigned short* B0  = (unsigned short*)(ws);              // 8 MB
    unsigned short* B1  = (unsigned short*)(ws +  8388608);   // 8 MB
    unsigned short* BT  = (unsigned short*)(ws + 16777216);   // 8 MB
    unsigned short* Mb  = (unsigned short*)(ws + 25165824);   // 8 MB
    float* base   = (float*)(ws + 33554432);
    float* rowsum = base;             // N
    float* colsum = base + 2048;      // N
    float* total  = base + 4096;
    float* sumsq_y = base + 4097;
    float* sumsq_v = base + 4098;
    float* inv_s   = base + 4099;
    float* va = base + 4100;          // N (16B-aligned)
    float* vb = base + 6148;          // N
    float* yv = base + 8196;          // N

    const dim3 gg(16, 16);            // 256 GEMM blocks (1/CU)
    const dim3 gt(32, 32);            // 64x64 tile kernels

    hipMemsetAsync(colsum, 0, (size_t)N * sizeof(float), stream);

    // ---- projection: X = P H P  (fp32 -> Xf, bf16 -> B0) ----
    rowsum_kernel<<<N, 256, 0, stream>>>(H_raw, rowsum);
    colsum_kernel<<<dim3(8, 32), 256, 0, stream>>>(H_raw, colsum);
    total_kernel<<<1, 256, 0, stream>>>(rowsum, total);
    project_kernel<<<4096, 256, 0, stream>>>(H_raw, rowsum, colsum, total, Xf, B0);

    // ---- spectral-norm estimate: 2 Gram power iterations + Rayleigh ----
    init_v<<<8, 256, 0, stream>>>(va);
    float *pa = va, *pb = vb;
    for (int it = 0; it < 2; ++it) {
        matvec_row<<<256, 256, 0, stream>>>(B0, pa, yv);
        hipMemsetAsync(pb, 0, N * sizeof(float), stream);
        matvec_colT<<<dim3(8, 32), 256, 0, stream>>>(B0, yv, pb);
        float* t = pa; pa = pb; pb = t;
    }
    sumsq_kernel<<<1, 256, 0, stream>>>(pa, sumsq_v);
    matvec_row<<<256, 256, 0, stream>>>(B0, pa, yv);
    sumsq_kernel<<<1, 256, 0, stream>>>(yv, sumsq_y);
    rayleigh_kernel<<<1, 1, 0, stream>>>(sumsq_y, sumsq_v, inv_s);
    scale_kernel<<<gt, 256, 0, stream>>>(Xf, inv_s, B0, BT);   // B0 = X/s, BT = B0^T

    // ---- 2 tuned NS steps: B <- B(a - b B^T B) ----
    // step 1: tuned (a,b) = (1.8467, 0.8815) -- maps [0.67,0.99] -> [0.97,1.03]
    gemm_bt<1><<<gg, 256, 0, stream>>>(B0, B0, Mb, nullptr, 1.8467f, 0.8815f);
    gemm_bt<2><<<gg, 256, 0, stream>>>(Mb, BT, B1, nullptr, 0.f, 0.f);   // B1 = M B0
    transpose_kernel<<<gt, 256, 0, stream>>>(B1, BT);
    // step 2: vanilla (1.5, 0.5); H = M2 B1 + (1/n) 1 1^T  straight to d_out
    gemm_bt<1><<<gg, 256, 0, stream>>>(B1, B1, Mb, nullptr, 1.5f, 0.5f);
    gemm_bt<3><<<gg, 256, 0, stream>>>(Mb, BT, nullptr, Xf, 0.f, 0.f);
}